// Round 6
// baseline (911.404 us; speedup 1.0000x reference)
//
#include <hip/hip_runtime.h>

// ---------------------------------------------------------------------------
// SLMGAE edge scorer, round 6.
//   P = zc @ fc1_w[0:400] + b1,  Q = zc @ fc1_w[400:800]   (per node)
//   per edge: h1 = relu(P[s]+Q[d]); h2 = relu(h1@W2+b2); h3 = relu(h2@W3+b3);
//   out = h3@w4 + b4
// Round-6 changes vs round 5 (edge: SIMD idle ~55%, weight loads un-hoisted
// because launch_bounds(256,3) left no reg headroom; non-edge ballooned):
//   * edge: launch_bounds(256,2) (honest 256-reg budget -> compiler can hoist
//     7 weight frags + pipeline), depth-2 gather prefetch, v_cvt_pk_bf16_f32
//     packing (guarded), persistent 2560-block grid.
//   * prep_w: source-linear indexing -> fc1/fc2/fc3 reads fully coalesced
//     (was 64-line scatter per load); edge histogram folded in (cnt zeroed
//     via hipMemsetAsync).
//   * edge_scan: 1024 threads.  node_gemm: y-split 10 -> 5 (half A refetch).
// ---------------------------------------------------------------------------

using u16    = unsigned short;
using bf16x8 = __attribute__((ext_vector_type(8))) short;   // 8 bf16 (4 VGPR)
using f32x4  = __attribute__((ext_vector_type(4))) float;
using f32x16 = __attribute__((ext_vector_type(16))) float;
using i32x4  = __attribute__((ext_vector_type(4))) int;

#define NN   20000   // nodes
#define NNP  20032   // nodes padded (multiple of 64)
#define KD   416     // 400 padded to multiple of 32 (col 400 = bias-one)
#define NE   500000  // edges

// fragment-order element counts
#define W1F_ELEMS (50*13*512)    // 50 n-tiles(16) x 13 kb(32) x 64 lanes x 8
#define W2F_ELEMS (26*7*512)     // kb-major: 26 kb(16) x 7 n-tiles(32) x 64 x 8
#define W3F_ELEMS (14*4*512)     // kb-major: 14 kb(16) x 4 n-tiles(32) x 64 x 8
#define F4_ELEMS  128
#define CNT_N  20480             // histogram bins (1024*20), >= NN, zero-padded

// prep_w source-linear ranges
#define R1 (416*800)             // W1f build        332800
#define R2 (416*224)             // W2f build         93184
#define R3 (224*128)             // W3f build         28672
#define R4 F4_ELEMS              // fc4wp               128
#define R5 (NE/4)                // histogram (int4) 125000
#define PREP_TOT (R1+R2+R3+R4+R5)

#define NTILES ((NE + 127) / 128)   // 3907 edge tiles of 128
#define EGRID  2560                 // persistent edge grid (10 blocks/CU)

__device__ __forceinline__ u16 f2bf(float f) {              // RNE f32->bf16
  unsigned u = __float_as_uint(f);
  u += 0x7fffu + ((u >> 16) & 1u);
  return (u16)(u >> 16);
}

// pack two f32 -> packed bf16 dword (lo in [15:0], hi in [31:16]), RNE
__device__ __forceinline__ int pk_bf16(float lo, float hi) {
#if __has_builtin(__builtin_amdgcn_cvt_pk_bf16_f32)
  auto t = __builtin_amdgcn_cvt_pk_bf16_f32(lo, hi);   // gfx950 v_cvt_pk_bf16_f32
  int r;
  __builtin_memcpy(&r, &t, 4);
  return r;
#else
  unsigned ul = __float_as_uint(lo); ul += 0x7fffu + ((ul >> 16) & 1u);
  unsigned uh = __float_as_uint(hi); uh += 0x7fffu + ((uh >> 16) & 1u);
  return (int)((ul >> 16) | (uh & 0xFFFF0000u));
#endif
}

// ---------------------------------------------------------------------------
// K0: weight prep, SOURCE-LINEAR (coalesced reads, mildly scattered 2B
// writes) + edge histogram folded in. cnt must be pre-zeroed (memsetAsync).
//  Frag layouts (match consumers):
//   W1f: dst = ((g*13+kb)*64 + ((k>>3)&3)*16 + (n&15))*8 + (k&7), g=n>>4,kb=k>>5
//   W2f: dst = ((kb*7+nt)*64 + ((k>>3)&1)*32 + (n&31))*8 + (k&7), kb=k>>4,nt=n>>5
//   W3f: dst = ((kb*4+nt)*64 + ((k>>3)&1)*32 + (n&31))*8 + (k&7), kb=k>>4,nt=n>>5
// ---------------------------------------------------------------------------
__global__ __launch_bounds__(256) void prep_w(
    const float* __restrict__ fc1, const float* __restrict__ fc1b,
    const float* __restrict__ fc2, const float* __restrict__ fc2b,
    const float* __restrict__ fc3, const float* __restrict__ fc3b,
    const float* __restrict__ fc4, const int* __restrict__ ei,
    u16* __restrict__ W1f, u16* __restrict__ W2f, u16* __restrict__ W3f,
    float* __restrict__ fc4wp, int* __restrict__ cnt)
{
  int idx = blockIdx.x * 256 + threadIdx.x;
  if (idx < R1) {
    int k = idx / 800, n = idx - k * 800;         // read coalesced in n
    float v = 0.f;
    if (k < 400) v = (n < 400) ? fc1[(size_t)k * 400 + n]
                               : fc1[(size_t)(400 + k) * 400 + (n - 400)];
    else if (k == 400 && n < 400) v = fc1b[n];
    int dst = (((n >> 4) * 13 + (k >> 5)) * 64 + ((k >> 3) & 3) * 16 + (n & 15)) * 8 + (k & 7);
    W1f[dst] = f2bf(v);
  } else if (idx < R1 + R2) {
    int r = idx - R1;
    int k = r / 224, n = r - k * 224;
    float v = 0.f;
    if (n < 200) {
      if (k < 400) v = fc2[(size_t)k * 200 + n];
      else if (k == 400) v = fc2b[n];
    }
    int dst = (((k >> 4) * 7 + (n >> 5)) * 64 + ((k >> 3) & 1) * 32 + (n & 31)) * 8 + (k & 7);
    W2f[dst] = f2bf(v);
  } else if (idx < R1 + R2 + R3) {
    int r = idx - (R1 + R2);
    int k = r >> 7, n = r & 127;
    float v = 0.f;
    if (n < 100) {
      if (k < 200) v = fc3[(size_t)k * 100 + n];
      else if (k == 200) v = fc3b[n];
    }
    int dst = (((k >> 4) * 4 + (n >> 5)) * 64 + ((k >> 3) & 1) * 32 + (n & 31)) * 8 + (k & 7);
    W3f[dst] = f2bf(v);
  } else if (idx < R1 + R2 + R3 + R4) {
    int r = idx - (R1 + R2 + R3);
    fc4wp[r] = (r < 100) ? fc4[r] : 0.f;
  } else if (idx < PREP_TOT) {
    int e4 = (idx - (R1 + R2 + R3 + R4)) * 4;
    int4 v = *(const int4*)(ei + e4);
    atomicAdd(&cnt[v.x], 1); atomicAdd(&cnt[v.y], 1);
    atomicAdd(&cnt[v.z], 1); atomicAdd(&cnt[v.w], 1);
  }
}

// ---------------------------------------------------------------------------
// Exclusive scan of cnt -> ofs (1024 threads, 20 bins each).
// ---------------------------------------------------------------------------
__global__ __launch_bounds__(1024) void edge_scan(
    const int* __restrict__ cnt, int* __restrict__ ofs)
{
  __shared__ int part[1024];
  int t = threadIdx.x, base = t * 20;
  int loc[20];
  int sum = 0;
  #pragma unroll
  for (int i = 0; i < 20; i++) { loc[i] = cnt[base + i]; sum += loc[i]; }
  part[t] = sum;
  __syncthreads();
  for (int d2 = 1; d2 < 1024; d2 <<= 1) {
    int v = (t >= d2) ? part[t - d2] : 0;
    __syncthreads();
    part[t] += v;
    __syncthreads();
  }
  int run = part[t] - sum;                 // exclusive base of this chunk
  #pragma unroll
  for (int i = 0; i < 20; i++) { ofs[base + i] = run; run += loc[i]; }
}

__global__ __launch_bounds__(256) void edge_scatter(
    const int* __restrict__ ei, int* __restrict__ ofs,
    int* __restrict__ ss, int* __restrict__ dd, int* __restrict__ eo)
{
  int e4 = (blockIdx.x * 256 + threadIdx.x) * 4;
  if (e4 < NE) {
    int4 sv = *(const int4*)(ei + e4);
    int4 dv = *(const int4*)(ei + NE + e4);
    #pragma unroll
    for (int t = 0; t < 4; t++) {
      int s = (t == 0) ? sv.x : (t == 1) ? sv.y : (t == 2) ? sv.z : sv.w;
      int d = (t == 0) ? dv.x : (t == 1) ? dv.y : (t == 2) ? dv.z : dv.w;
      int pos = atomicAdd(&ofs[s], 1);
      ss[pos] = s; dd[pos] = d; eo[pos] = e4 + t;
    }
  }
}

// ---------------------------------------------------------------------------
// K1: per-node tiny MLP (4->64->32->16 fp32) + build zc_bf [NNP][416]
//     zc = [z(64) | m(16) | esm(320) | 1.0 at k=400 | zeros]
// ---------------------------------------------------------------------------
__global__ __launch_bounds__(256) void build_zc(
    const float* __restrict__ z, const float* __restrict__ cell,
    const float* __restrict__ esm,
    const float* __restrict__ w1, const float* __restrict__ b1,
    const float* __restrict__ w2, const float* __restrict__ b2,
    const float* __restrict__ w3, const float* __restrict__ b3,
    u16* __restrict__ zc)
{
  __shared__ float h1s[4][64];
  __shared__ float h2s[4][32];
  __shared__ float ms[4][16];
  int tid = threadIdx.x, g = tid >> 6, t = tid & 63;
  int i = blockIdx.x * 4 + g;
  bool real = (i < NN);
  float c0 = 0, c1 = 0, c2 = 0, c3 = 0;
  if (real) {
    c0 = cell[(size_t)i * 4 + 0]; c1 = cell[(size_t)i * 4 + 1];
    c2 = cell[(size_t)i * 4 + 2]; c3 = cell[(size_t)i * 4 + 3];
  }
  float h = b1[t] + c0 * w1[t] + c1 * w1[64 + t] + c2 * w1[128 + t] + c3 * w1[192 + t];
  h1s[g][t] = fmaxf(h, 0.f);
  __syncthreads();
  if (t < 32) {
    float acc = b2[t];
    #pragma unroll 8
    for (int j = 0; j < 64; j++) acc += h1s[g][j] * w2[j * 32 + t];
    h2s[g][t] = fmaxf(acc, 0.f);
  }
  __syncthreads();
  if (t < 16) {
    float acc = b3[t];
    #pragma unroll 8
    for (int j = 0; j < 32; j++) acc += h2s[g][j] * w3[j * 16 + t];
    ms[g][t] = acc;
  }
  __syncthreads();
  u16* row = zc + (size_t)i * KD;
  for (int k = t; k < KD; k += 64) {
    float v = 0.f;
    if (real) {
      if (k < 64)       v = z[(size_t)i * 64 + k];
      else if (k < 80)  v = ms[g][k - 64];
      else if (k < 400) v = esm[(size_t)i * 320 + (k - 80)];
      else if (k == 400) v = 1.0f;     // bias-one column (fc1b lives in W1f)
    }
    row[k] = f2bf(v);
  }
}

// ---------------------------------------------------------------------------
// K2: PQ[NNP][800] = zc_bf @ W1^T (bias via k=400 col), bf16 out.
// Dual 16-row A-tiles per wave; grid (157, 5): y = group of 10 col-tiles.
// ---------------------------------------------------------------------------
__global__ __launch_bounds__(256) void node_gemm(
    const u16* __restrict__ zc, const u16* __restrict__ W1f,
    u16* __restrict__ PQ)
{
  int tid = threadIdx.x, w = tid >> 6, l = tid & 63, lm = l & 15, quad = l >> 4;
  int mbase = blockIdx.x * 128 + w * 32;

  int ra = mbase + lm;       if (ra > NNP - 1) ra = NNP - 1;
  int rb = mbase + 16 + lm;  if (rb > NNP - 1) rb = NNP - 1;
  bf16x8 a0[13], a1[13];
  const u16* arow0 = zc + (size_t)ra * KD + quad * 8;
  const u16* arow1 = zc + (size_t)rb * KD + quad * 8;
  #pragma unroll
  for (int kb = 0; kb < 13; kb++) {
    a0[kb] = *(const bf16x8*)(arow0 + kb * 32);
    a1[kb] = *(const bf16x8*)(arow1 + kb * 32);
  }

  for (int nt = 0; nt < 10; nt++) {
    int g = blockIdx.y * 10 + nt;          // global 16-col tile (0..49)
    int ncol = g * 16 + lm;
    const u16* bbase = W1f + ((size_t)g * 13 * 64 + l) * 8;
    f32x4 acc0 = {0.f, 0.f, 0.f, 0.f};
    f32x4 acc1 = {0.f, 0.f, 0.f, 0.f};
    #pragma unroll
    for (int kb = 0; kb < 13; kb++) {
      bf16x8 b = *(const bf16x8*)(bbase + (size_t)kb * 512);
      acc0 = __builtin_amdgcn_mfma_f32_16x16x32_bf16(a0[kb], b, acc0, 0, 0, 0);
      acc1 = __builtin_amdgcn_mfma_f32_16x16x32_bf16(a1[kb], b, acc1, 0, 0, 0);
    }
    #pragma unroll
    for (int r = 0; r < 4; r++) {
      int row0 = mbase + quad * 4 + r;
      int row1 = row0 + 16;
      if (row0 < NNP) PQ[(size_t)row0 * 800 + ncol] = f2bf(acc0[r]);
      if (row1 < NNP) PQ[(size_t)row1 * 800 + ncol] = f2bf(acc1[r]);
    }
  }
}

// ---------------------------------------------------------------------------
// K3: edge kernel — persistent grid, 32 sorted edges/wave, mfma 32x32x16,
// kb-outer fused gather+fc2, weights direct from L2 (frag order), no LDS.
// launch_bounds(256,2): full 256-reg budget -> compiler hoists weight frags
// and pipelines the depth-2 gather prefetch without spilling.
// ---------------------------------------------------------------------------
__global__ __launch_bounds__(256, 2) void edge_kernel(
    const u16* __restrict__ PQ, const u16* __restrict__ W2f,
    const u16* __restrict__ W3f, const float* __restrict__ fc4wp,
    const float* __restrict__ fc4b,
    const int* __restrict__ ss, const int* __restrict__ dd,
    const int* __restrict__ eo, float* __restrict__ out)
{
  int tid = threadIdx.x, w = tid >> 6, l = tid & 63;
  int c = l & 31, h = l >> 5;
  float b4 = fc4b[0];

  for (int tile = blockIdx.x; tile < NTILES; tile += EGRID) {
    int i = tile * 128 + w * 32 + c;
    int ic = i < NE ? i : NE - 1;
    int s = ss[ic], d = dd[ic], oe = eo[ic];
    const u16* prow = PQ + (size_t)s * 800 + h * 8;        // P (pre-biased)
    const u16* qrow = PQ + (size_t)d * 800 + 400 + h * 8;  // Q

    // ---- fc2, kb-outer: gather frag just-in-time, feed 7 accumulators ----
    f32x16 acc[7];
    #pragma unroll
    for (int nt = 0; nt < 7; nt++)
      acc[nt] = (f32x16){0.f,0.f,0.f,0.f,0.f,0.f,0.f,0.f,
                         0.f,0.f,0.f,0.f,0.f,0.f,0.f,0.f};

    i32x4 pv0 = *(const i32x4*)(prow);
    i32x4 qv0 = *(const i32x4*)(qrow);
    i32x4 pv1 = *(const i32x4*)(prow + 16);
    i32x4 qv1 = *(const i32x4*)(qrow + 16);
    for (int kb = 0; kb < 25; kb++) {
      // build h1 B-frag for this kb (bf16 add + relu + RNE pack)
      i32x4 fr;
      #pragma unroll
      for (int j2 = 0; j2 < 4; j2++) {
        unsigned pu = (unsigned)pv0[j2], qu = (unsigned)qv0[j2];
        float lo = __uint_as_float(pu << 16) + __uint_as_float(qu << 16);
        float hi = __uint_as_float(pu & 0xFFFF0000u) + __uint_as_float(qu & 0xFFFF0000u);
        fr[j2] = pk_bf16(fmaxf(lo, 0.f), fmaxf(hi, 0.f));
      }
      pv0 = pv1; qv0 = qv1;
      if (kb + 2 < 25) {                       // depth-2 prefetch
        pv1 = *(const i32x4*)(prow + (kb + 2) * 16);
        qv1 = *(const i32x4*)(qrow + (kb + 2) * 16);
      }
      const u16* wb = W2f + ((size_t)(kb * 7) * 64 + l) * 8;   // 7 KB, kb-major
      #pragma unroll
      for (int nt = 0; nt < 7; nt++) {
        bf16x8 a = *(const bf16x8*)(wb + nt * 512);
        acc[nt] = __builtin_amdgcn_mfma_f32_32x32x16_bf16(
            a, __builtin_bit_cast(bf16x8, fr), acc[nt], 0, 0, 0);
      }
    }
    {  // kb = 25: bias column k=400 (h1[k=400] = 1.0)
      i32x4 fr = {0, 0, 0, 0};
      if (h == 0) fr[0] = 0x3f80;
      const u16* wb = W2f + ((size_t)(25 * 7) * 64 + l) * 8;
      #pragma unroll
      for (int nt = 0; nt < 7; nt++) {
        bf16x8 a = *(const bf16x8*)(wb + nt * 512);
        acc[nt] = __builtin_amdgcn_mfma_f32_32x32x16_bf16(
            a, __builtin_bit_cast(bf16x8, fr), acc[nt], 0, 0, 0);
      }
    }

    // ---- relu + pack h2 (accs die in order) -------------------------------
    int p2[7][8];
    #pragma unroll
    for (int nt = 0; nt < 7; nt++) {
      #pragma unroll
      for (int q = 0; q < 8; q++)
        p2[nt][q] = pk_bf16(fmaxf(acc[nt][2 * q], 0.f),
                            fmaxf(acc[nt][2 * q + 1], 0.f));
    }

    // ---- transpose: C-layout h2 -> fc3 B-frags via shfl_xor(32) -----------
    i32x4 b2f[14];
    #pragma unroll
    for (int kb3 = 0; kb3 < 14; kb3++) {
      int nt = kb3 >> 1;
      i32x4 f;
      #pragma unroll
      for (int jj = 0; jj < 4; jj++) {
        int q0 = (jj & 1) + 4 * (kb3 & 1);
        if (jj < 2) {        // source lives in lower half (h_s = 0)
          int x = __shfl_xor(p2[nt][q0 + 2], 32);
          f[jj] = h ? x : p2[nt][q0];
        } else {             // source lives in upper half (h_s = 1)
          int y = __shfl_xor(p2[nt][q0], 32);
          f[jj] = h ? p2[nt][q0 + 2] : y;
        }
      }
      if (kb3 == 12 && h) f[0] |= 0x3f80;   // h2[k2=200] = 1.0 (fc3 bias-one)
      b2f[kb3] = f;
    }

    // ---- fc3 kb-outer + fc4 -----------------------------------------------
    f32x16 acc3[4];
    #pragma unroll
    for (int nt3 = 0; nt3 < 4; nt3++)
      acc3[nt3] = (f32x16){0.f,0.f,0.f,0.f,0.f,0.f,0.f,0.f,
                           0.f,0.f,0.f,0.f,0.f,0.f,0.f,0.f};
    for (int kb3 = 0; kb3 < 14; kb3++) {
      const u16* wb3 = W3f + ((size_t)(kb3 * 4) * 64 + l) * 8;  // 4 KB
      #pragma unroll
      for (int nt3 = 0; nt3 < 4; nt3++) {
        bf16x8 a = *(const bf16x8*)(wb3 + nt3 * 512);
        acc3[nt3] = __builtin_amdgcn_mfma_f32_32x32x16_bf16(
            a, __builtin_bit_cast(bf16x8, b2f[kb3]), acc3[nt3], 0, 0, 0);
      }
    }
    float osum = 0.f;
    #pragma unroll
    for (int nt3 = 0; nt3 < 4; nt3++) {
      #pragma unroll
      for (int r = 0; r < 16; r++) {
        int rho = (r & 3) + 8 * (r >> 2) + 4 * h + 32 * nt3;
        osum += fmaxf(acc3[nt3][r], 0.f) * fc4wp[rho];   // pad rows: 0 * 0
      }
    }
    osum += __shfl_xor(osum, 32);   // combine the two k-halves of this edge
    if (h == 0 && i < NE) out[oe] = osum + b4;
  }
}

// ---------------------------------------------------------------------------
extern "C" void kernel_launch(void* const* d_in, const int* in_sizes, int n_in,
                              void* d_out, int out_size, void* d_ws, size_t ws_size,
                              hipStream_t stream) {
  (void)in_sizes; (void)n_in; (void)out_size; (void)ws_size;
  const float* z    = (const float*)d_in[0];
  const int*   ei   = (const int*)d_in[1];
  const float* cell = (const float*)d_in[2];
  const float* esm  = (const float*)d_in[3];
  const float* w1   = (const float*)d_in[4];
  const float* b1   = (const float*)d_in[5];
  const float* w2   = (const float*)d_in[6];
  const float* b2   = (const float*)d_in[7];
  const float* w3   = (const float*)d_in[8];
  const float* b3   = (const float*)d_in[9];
  const float* fc1w = (const float*)d_in[10];
  const float* fc1b = (const float*)d_in[11];
  const float* fc2w = (const float*)d_in[12];
  const float* fc2b = (const float*)d_in[13];
  const float* fc3w = (const float*)d_in[14];
  const float* fc3b = (const float*)d_in[15];
  const float* fc4w = (const float*)d_in[16];
  const float* fc4b = (const float*)d_in[17];
  float* out = (float*)d_out;

  // workspace layout (u16 units then ints, all 16B-aligned): ~56 MB
  u16* zc  = (u16*)d_ws;                        // NNP*416
  u16* PQ  = zc  + (size_t)NNP * KD;            // NNP*800
  u16* W1f = PQ  + (size_t)NNP * 800;           // 332800
  u16* W2f = W1f + W1F_ELEMS;                   // 93184
  u16* W3f = W2f + W2F_ELEMS;                   // 28672
  float* fc4wp = (float*)(W3f + W3F_ELEMS);     // 128 f32
  int* cnt = (int*)(fc4wp + F4_ELEMS);          // 20480
  int* ofs = cnt + CNT_N;                       // 20480
  int* ss  = ofs + CNT_N;                       // 500000
  int* dd  = ss + NE;                           // 500000
  int* eo  = dd + NE;                           // 500000

  hipMemsetAsync(cnt, 0, CNT_N * sizeof(int), stream);
  prep_w<<<(PREP_TOT + 255) / 256, 256, 0, stream>>>(
      fc1w, fc1b, fc2w, fc2b, fc3w, fc3b, fc4w, ei, W1f, W2f, W3f, fc4wp, cnt);
  edge_scan<<<1, 1024, 0, stream>>>(cnt, ofs);
  edge_scatter<<<(NE / 4 + 255) / 256, 256, 0, stream>>>(ei, ofs, ss, dd, eo);
  build_zc<<<NNP / 4, 256, 0, stream>>>(z, cell, esm, w1, b1, w2, b2, w3, b3, zc);
  node_gemm<<<dim3((NNP + 127) / 128, 5), 256, 0, stream>>>(zc, W1f, PQ);
  edge_kernel<<<EGRID, 256, 0, stream>>>(
      PQ, W2f, W3f, fc4wp, fc4b, ss, dd, eo, out);
}

// Round 7
// 535.414 us; speedup vs baseline: 1.7022x; 1.7022x over previous
//
#include <hip/hip_runtime.h>

// ---------------------------------------------------------------------------
// SLMGAE edge scorer, round 7 = round-5 edge kernel (known-good 313 us,
// no spill) + round-6 non-edge pipeline (86 us) + XCD-aware tile swizzle.
//   P = zc @ fc1_w[0:400] + b1,  Q = zc @ fc1_w[400:800]   (per node)
//   per edge: h1 = relu(P[s]+Q[d]); h2 = relu(h1@W2+b2); h3 = relu(h2@W3+b3);
//   out = h3@w4 + b4
// Round-6 lesson: launch_bounds(256,2)+persistent loop => compiler spill
// (WRITE 578 MB). Edge kernel reverted verbatim to round-5 (launch_bounds
// (256,3), depth-1 prefetch, manual RNE pack). New: consecutive sorted tiles
// are given to the SAME XCD via tile = (bid&7)*489 + bid>>3, so the L2 that
// fetched a source row's P-line serves all its edges (dispatch round-robins
// blockIdx across the 8 XCDs).
// ---------------------------------------------------------------------------

using u16    = unsigned short;
using bf16x8 = __attribute__((ext_vector_type(8))) short;   // 8 bf16 (4 VGPR)
using f32x4  = __attribute__((ext_vector_type(4))) float;
using f32x16 = __attribute__((ext_vector_type(16))) float;
using i32x4  = __attribute__((ext_vector_type(4))) int;

#define NN   20000   // nodes
#define NNP  20032   // nodes padded (multiple of 64)
#define KD   416     // 400 padded to multiple of 32 (col 400 = bias-one)
#define NE   500000  // edges

// fragment-order element counts
#define W1F_ELEMS (50*13*512)    // 50 n-tiles(16) x 13 kb(32) x 64 lanes x 8
#define W2F_ELEMS (26*7*512)     // kb-major: 26 kb(16) x 7 n-tiles(32) x 64 x 8
#define W3F_ELEMS (14*4*512)     // kb-major: 14 kb(16) x 4 n-tiles(32) x 64 x 8
#define F4_ELEMS  128
#define CNT_N  20480             // histogram bins (1024*20), >= NN, zero-padded

// prep_w source-linear ranges
#define R1 (416*800)             // W1f build        332800
#define R2 (416*224)             // W2f build         93184
#define R3 (224*128)             // W3f build         28672
#define R4 F4_ELEMS              // fc4wp               128
#define R5 (NE/4)                // histogram (int4) 125000
#define PREP_TOT (R1+R2+R3+R4+R5)

#define NTILES ((NE + 127) / 128)   // 3907 edge tiles of 128
#define TCHUNK ((NTILES + 7) / 8)   // 489 tiles per XCD
#define EGRID  (TCHUNK * 8)         // 3912 blocks

__device__ __forceinline__ u16 f2bf(float f) {              // RNE f32->bf16
  unsigned u = __float_as_uint(f);
  u += 0x7fffu + ((u >> 16) & 1u);
  return (u16)(u >> 16);
}

// ---------------------------------------------------------------------------
// K0: weight prep, SOURCE-LINEAR (coalesced reads, mildly scattered 2B
// writes) + edge histogram folded in. cnt must be pre-zeroed (memsetAsync).
//  Frag layouts (match consumers):
//   W1f: dst = ((g*13+kb)*64 + ((k>>3)&3)*16 + (n&15))*8 + (k&7), g=n>>4,kb=k>>5
//   W2f: dst = ((kb*7+nt)*64 + ((k>>3)&1)*32 + (n&31))*8 + (k&7), kb=k>>4,nt=n>>5
//   W3f: dst = ((kb*4+nt)*64 + ((k>>3)&1)*32 + (n&31))*8 + (k&7), kb=k>>4,nt=n>>5
// ---------------------------------------------------------------------------
__global__ __launch_bounds__(256) void prep_w(
    const float* __restrict__ fc1, const float* __restrict__ fc1b,
    const float* __restrict__ fc2, const float* __restrict__ fc2b,
    const float* __restrict__ fc3, const float* __restrict__ fc3b,
    const float* __restrict__ fc4, const int* __restrict__ ei,
    u16* __restrict__ W1f, u16* __restrict__ W2f, u16* __restrict__ W3f,
    float* __restrict__ fc4wp, int* __restrict__ cnt)
{
  int idx = blockIdx.x * 256 + threadIdx.x;
  if (idx < R1) {
    int k = idx / 800, n = idx - k * 800;         // read coalesced in n
    float v = 0.f;
    if (k < 400) v = (n < 400) ? fc1[(size_t)k * 400 + n]
                               : fc1[(size_t)(400 + k) * 400 + (n - 400)];
    else if (k == 400 && n < 400) v = fc1b[n];
    int dst = (((n >> 4) * 13 + (k >> 5)) * 64 + ((k >> 3) & 3) * 16 + (n & 15)) * 8 + (k & 7);
    W1f[dst] = f2bf(v);
  } else if (idx < R1 + R2) {
    int r = idx - R1;
    int k = r / 224, n = r - k * 224;
    float v = 0.f;
    if (n < 200) {
      if (k < 400) v = fc2[(size_t)k * 200 + n];
      else if (k == 400) v = fc2b[n];
    }
    int dst = (((k >> 4) * 7 + (n >> 5)) * 64 + ((k >> 3) & 1) * 32 + (n & 31)) * 8 + (k & 7);
    W2f[dst] = f2bf(v);
  } else if (idx < R1 + R2 + R3) {
    int r = idx - (R1 + R2);
    int k = r >> 7, n = r & 127;
    float v = 0.f;
    if (n < 100) {
      if (k < 200) v = fc3[(size_t)k * 100 + n];
      else if (k == 200) v = fc3b[n];
    }
    int dst = (((k >> 4) * 4 + (n >> 5)) * 64 + ((k >> 3) & 1) * 32 + (n & 31)) * 8 + (k & 7);
    W3f[dst] = f2bf(v);
  } else if (idx < R1 + R2 + R3 + R4) {
    int r = idx - (R1 + R2 + R3);
    fc4wp[r] = (r < 100) ? fc4[r] : 0.f;
  } else if (idx < PREP_TOT) {
    int e4 = (idx - (R1 + R2 + R3 + R4)) * 4;
    int4 v = *(const int4*)(ei + e4);
    atomicAdd(&cnt[v.x], 1); atomicAdd(&cnt[v.y], 1);
    atomicAdd(&cnt[v.z], 1); atomicAdd(&cnt[v.w], 1);
  }
}

// ---------------------------------------------------------------------------
// Exclusive scan of cnt -> ofs (1024 threads, 20 bins each).
// ---------------------------------------------------------------------------
__global__ __launch_bounds__(1024) void edge_scan(
    const int* __restrict__ cnt, int* __restrict__ ofs)
{
  __shared__ int part[1024];
  int t = threadIdx.x, base = t * 20;
  int loc[20];
  int sum = 0;
  #pragma unroll
  for (int i = 0; i < 20; i++) { loc[i] = cnt[base + i]; sum += loc[i]; }
  part[t] = sum;
  __syncthreads();
  for (int d2 = 1; d2 < 1024; d2 <<= 1) {
    int v = (t >= d2) ? part[t - d2] : 0;
    __syncthreads();
    part[t] += v;
    __syncthreads();
  }
  int run = part[t] - sum;                 // exclusive base of this chunk
  #pragma unroll
  for (int i = 0; i < 20; i++) { ofs[base + i] = run; run += loc[i]; }
}

__global__ __launch_bounds__(256) void edge_scatter(
    const int* __restrict__ ei, int* __restrict__ ofs,
    int* __restrict__ ss, int* __restrict__ dd, int* __restrict__ eo)
{
  int e4 = (blockIdx.x * 256 + threadIdx.x) * 4;
  if (e4 < NE) {
    int4 sv = *(const int4*)(ei + e4);
    int4 dv = *(const int4*)(ei + NE + e4);
    #pragma unroll
    for (int t = 0; t < 4; t++) {
      int s = (t == 0) ? sv.x : (t == 1) ? sv.y : (t == 2) ? sv.z : sv.w;
      int d = (t == 0) ? dv.x : (t == 1) ? dv.y : (t == 2) ? dv.z : dv.w;
      int pos = atomicAdd(&ofs[s], 1);
      ss[pos] = s; dd[pos] = d; eo[pos] = e4 + t;
    }
  }
}

// ---------------------------------------------------------------------------
// K1: per-node tiny MLP (4->64->32->16 fp32) + build zc_bf [NNP][416]
//     zc = [z(64) | m(16) | esm(320) | 1.0 at k=400 | zeros]
// ---------------------------------------------------------------------------
__global__ __launch_bounds__(256) void build_zc(
    const float* __restrict__ z, const float* __restrict__ cell,
    const float* __restrict__ esm,
    const float* __restrict__ w1, const float* __restrict__ b1,
    const float* __restrict__ w2, const float* __restrict__ b2,
    const float* __restrict__ w3, const float* __restrict__ b3,
    u16* __restrict__ zc)
{
  __shared__ float h1s[4][64];
  __shared__ float h2s[4][32];
  __shared__ float ms[4][16];
  int tid = threadIdx.x, g = tid >> 6, t = tid & 63;
  int i = blockIdx.x * 4 + g;
  bool real = (i < NN);
  float c0 = 0, c1 = 0, c2 = 0, c3 = 0;
  if (real) {
    c0 = cell[(size_t)i * 4 + 0]; c1 = cell[(size_t)i * 4 + 1];
    c2 = cell[(size_t)i * 4 + 2]; c3 = cell[(size_t)i * 4 + 3];
  }
  float h = b1[t] + c0 * w1[t] + c1 * w1[64 + t] + c2 * w1[128 + t] + c3 * w1[192 + t];
  h1s[g][t] = fmaxf(h, 0.f);
  __syncthreads();
  if (t < 32) {
    float acc = b2[t];
    #pragma unroll 8
    for (int j = 0; j < 64; j++) acc += h1s[g][j] * w2[j * 32 + t];
    h2s[g][t] = fmaxf(acc, 0.f);
  }
  __syncthreads();
  if (t < 16) {
    float acc = b3[t];
    #pragma unroll 8
    for (int j = 0; j < 32; j++) acc += h2s[g][j] * w3[j * 16 + t];
    ms[g][t] = acc;
  }
  __syncthreads();
  u16* row = zc + (size_t)i * KD;
  for (int k = t; k < KD; k += 64) {
    float v = 0.f;
    if (real) {
      if (k < 64)       v = z[(size_t)i * 64 + k];
      else if (k < 80)  v = ms[g][k - 64];
      else if (k < 400) v = esm[(size_t)i * 320 + (k - 80)];
      else if (k == 400) v = 1.0f;     // bias-one column (fc1b lives in W1f)
    }
    row[k] = f2bf(v);
  }
}

// ---------------------------------------------------------------------------
// K2: PQ[NNP][800] = zc_bf @ W1^T (bias via k=400 col), bf16 out.
// Dual 16-row A-tiles per wave; grid (157, 5): y = group of 10 col-tiles.
// ---------------------------------------------------------------------------
__global__ __launch_bounds__(256) void node_gemm(
    const u16* __restrict__ zc, const u16* __restrict__ W1f,
    u16* __restrict__ PQ)
{
  int tid = threadIdx.x, w = tid >> 6, l = tid & 63, lm = l & 15, quad = l >> 4;
  int mbase = blockIdx.x * 128 + w * 32;

  int ra = mbase + lm;       if (ra > NNP - 1) ra = NNP - 1;
  int rb = mbase + 16 + lm;  if (rb > NNP - 1) rb = NNP - 1;
  bf16x8 a0[13], a1[13];
  const u16* arow0 = zc + (size_t)ra * KD + quad * 8;
  const u16* arow1 = zc + (size_t)rb * KD + quad * 8;
  #pragma unroll
  for (int kb = 0; kb < 13; kb++) {
    a0[kb] = *(const bf16x8*)(arow0 + kb * 32);
    a1[kb] = *(const bf16x8*)(arow1 + kb * 32);
  }

  for (int nt = 0; nt < 10; nt++) {
    int g = blockIdx.y * 10 + nt;          // global 16-col tile (0..49)
    int ncol = g * 16 + lm;
    const u16* bbase = W1f + ((size_t)g * 13 * 64 + l) * 8;
    f32x4 acc0 = {0.f, 0.f, 0.f, 0.f};
    f32x4 acc1 = {0.f, 0.f, 0.f, 0.f};
    #pragma unroll
    for (int kb = 0; kb < 13; kb++) {
      bf16x8 b = *(const bf16x8*)(bbase + (size_t)kb * 512);
      acc0 = __builtin_amdgcn_mfma_f32_16x16x32_bf16(a0[kb], b, acc0, 0, 0, 0);
      acc1 = __builtin_amdgcn_mfma_f32_16x16x32_bf16(a1[kb], b, acc1, 0, 0, 0);
    }
    #pragma unroll
    for (int r = 0; r < 4; r++) {
      int row0 = mbase + quad * 4 + r;
      int row1 = row0 + 16;
      if (row0 < NNP) PQ[(size_t)row0 * 800 + ncol] = f2bf(acc0[r]);
      if (row1 < NNP) PQ[(size_t)row1 * 800 + ncol] = f2bf(acc1[r]);
    }
  }
}

// ---------------------------------------------------------------------------
// K3: edge kernel — round-5 structure verbatim (32 sorted edges/wave,
// mfma 32x32x16, kb-outer fused gather+fc2, weights direct from L2, no LDS)
// + XCD-aware tile swizzle: consecutive sorted tiles -> same XCD's L2.
// ---------------------------------------------------------------------------
__global__ __launch_bounds__(256, 3) void edge_kernel(
    const u16* __restrict__ PQ, const u16* __restrict__ W2f,
    const u16* __restrict__ W3f, const float* __restrict__ fc4wp,
    const float* __restrict__ fc4b,
    const int* __restrict__ ss, const int* __restrict__ dd,
    const int* __restrict__ eo, float* __restrict__ out)
{
  // blockIdx round-robins across 8 XCDs; give XCD x the contiguous sorted
  // tile range [x*TCHUNK, (x+1)*TCHUNK) so its L2 owns those source rows.
  int bid = blockIdx.x;
  int tile = (bid & 7) * TCHUNK + (bid >> 3);
  if (tile >= NTILES) return;

  int tid = threadIdx.x, w = tid >> 6, l = tid & 63;
  int c = l & 31, h = l >> 5;
  int i = tile * 128 + w * 32 + c;
  int ic = i < NE ? i : NE - 1;
  int s = ss[ic], d = dd[ic], oe = eo[ic];
  const u16* prow = PQ + (size_t)s * 800 + h * 8;        // P (pre-biased)
  const u16* qrow = PQ + (size_t)d * 800 + 400 + h * 8;  // Q

  // ---- fc2, kb-outer: gather frag just-in-time, feed 7 accumulators ------
  f32x16 acc[7];
  #pragma unroll
  for (int nt = 0; nt < 7; nt++)
    acc[nt] = (f32x16){0.f,0.f,0.f,0.f,0.f,0.f,0.f,0.f,
                       0.f,0.f,0.f,0.f,0.f,0.f,0.f,0.f};

  i32x4 pv = *(const i32x4*)(prow);
  i32x4 qv = *(const i32x4*)(qrow);
  for (int kb = 0; kb < 25; kb++) {
    // build h1 B-frag for this kb (bf16 add + relu + RNE pack)
    i32x4 fr;
    #pragma unroll
    for (int j2 = 0; j2 < 4; j2++) {
      unsigned pu = (unsigned)pv[j2], qu = (unsigned)qv[j2];
      float lo = __uint_as_float(pu << 16) + __uint_as_float(qu << 16);
      float hi = __uint_as_float(pu & 0xFFFF0000u) + __uint_as_float(qu & 0xFFFF0000u);
      lo = fmaxf(lo, 0.f);
      hi = fmaxf(hi, 0.f);
      unsigned ul = __float_as_uint(lo); ul += 0x7fffu + ((ul >> 16) & 1u);
      unsigned uh = __float_as_uint(hi); uh += 0x7fffu + ((uh >> 16) & 1u);
      fr[j2] = (int)((ul >> 16) | (uh & 0xFFFF0000u));
    }
    if (kb < 24) {                         // prefetch next gather slice
      pv = *(const i32x4*)(prow + (kb + 1) * 16);
      qv = *(const i32x4*)(qrow + (kb + 1) * 16);
    }
    const u16* wb = W2f + ((size_t)(kb * 7) * 64 + l) * 8;   // 7 KB, kb-major
    #pragma unroll
    for (int nt = 0; nt < 7; nt++) {
      bf16x8 a = *(const bf16x8*)(wb + nt * 512);
      acc[nt] = __builtin_amdgcn_mfma_f32_32x32x16_bf16(
          a, __builtin_bit_cast(bf16x8, fr), acc[nt], 0, 0, 0);
    }
  }
  {  // kb = 25: bias column k=400 (h1[k=400] = 1.0)
    i32x4 fr = {0, 0, 0, 0};
    if (h == 0) fr[0] = 0x3f80;
    const u16* wb = W2f + ((size_t)(25 * 7) * 64 + l) * 8;
    #pragma unroll
    for (int nt = 0; nt < 7; nt++) {
      bf16x8 a = *(const bf16x8*)(wb + nt * 512);
      acc[nt] = __builtin_amdgcn_mfma_f32_32x32x16_bf16(
          a, __builtin_bit_cast(bf16x8, fr), acc[nt], 0, 0, 0);
    }
  }

  // ---- relu + pack h2 (accs die in order) ---------------------------------
  int p2[7][8];
  #pragma unroll
  for (int nt = 0; nt < 7; nt++) {
    #pragma unroll
    for (int q = 0; q < 8; q++) {
      float v0 = fmaxf(acc[nt][2 * q], 0.f);
      float v1 = fmaxf(acc[nt][2 * q + 1], 0.f);
      unsigned u0 = __float_as_uint(v0); u0 += 0x7fffu + ((u0 >> 16) & 1u);
      unsigned u1 = __float_as_uint(v1); u1 += 0x7fffu + ((u1 >> 16) & 1u);
      p2[nt][q] = (int)((u0 >> 16) | (u1 & 0xFFFF0000u));
    }
  }

  // ---- transpose: C-layout h2 -> fc3 B-frags via shfl_xor(32) -------------
  i32x4 b2f[14];
  #pragma unroll
  for (int kb3 = 0; kb3 < 14; kb3++) {
    int nt = kb3 >> 1;
    i32x4 f;
    #pragma unroll
    for (int jj = 0; jj < 4; jj++) {
      int q0 = (jj & 1) + 4 * (kb3 & 1);
      if (jj < 2) {        // source lives in lower half (h_s = 0)
        int x = __shfl_xor(p2[nt][q0 + 2], 32);
        f[jj] = h ? x : p2[nt][q0];
      } else {             // source lives in upper half (h_s = 1)
        int y = __shfl_xor(p2[nt][q0], 32);
        f[jj] = h ? p2[nt][q0 + 2] : y;
      }
    }
    if (kb3 == 12 && h) f[0] |= 0x3f80;   // h2[k2=200] = 1.0 (fc3 bias-one)
    b2f[kb3] = f;
  }

  // ---- fc3 kb-outer + fc4 -------------------------------------------------
  f32x16 acc3[4];
  #pragma unroll
  for (int nt3 = 0; nt3 < 4; nt3++)
    acc3[nt3] = (f32x16){0.f,0.f,0.f,0.f,0.f,0.f,0.f,0.f,
                         0.f,0.f,0.f,0.f,0.f,0.f,0.f,0.f};
  for (int kb3 = 0; kb3 < 14; kb3++) {
    const u16* wb3 = W3f + ((size_t)(kb3 * 4) * 64 + l) * 8;  // 4 KB, kb-major
    #pragma unroll
    for (int nt3 = 0; nt3 < 4; nt3++) {
      bf16x8 a = *(const bf16x8*)(wb3 + nt3 * 512);
      acc3[nt3] = __builtin_amdgcn_mfma_f32_32x32x16_bf16(
          a, __builtin_bit_cast(bf16x8, b2f[kb3]), acc3[nt3], 0, 0, 0);
    }
  }
  float osum = 0.f;
  #pragma unroll
  for (int nt3 = 0; nt3 < 4; nt3++) {
    #pragma unroll
    for (int r = 0; r < 16; r++) {
      int rho = (r & 3) + 8 * (r >> 2) + 4 * h + 32 * nt3;
      osum += fmaxf(acc3[nt3][r], 0.f) * fc4wp[rho];   // pad rows: 0 * 0
    }
  }
  osum += __shfl_xor(osum, 32);     // combine the two k-halves of this edge
  if (h == 0 && i < NE) out[oe] = osum + fc4b[0];
}

// ---------------------------------------------------------------------------
extern "C" void kernel_launch(void* const* d_in, const int* in_sizes, int n_in,
                              void* d_out, int out_size, void* d_ws, size_t ws_size,
                              hipStream_t stream) {
  (void)in_sizes; (void)n_in; (void)out_size; (void)ws_size;
  const float* z    = (const float*)d_in[0];
  const int*   ei   = (const int*)d_in[1];
  const float* cell = (const float*)d_in[2];
  const float* esm  = (const float*)d_in[3];
  const float* w1   = (const float*)d_in[4];
  const float* b1   = (const float*)d_in[5];
  const float* w2   = (const float*)d_in[6];
  const float* b2   = (const float*)d_in[7];
  const float* w3   = (const float*)d_in[8];
  const float* b3   = (const float*)d_in[9];
  const float* fc1w = (const float*)d_in[10];
  const float* fc1b = (const float*)d_in[11];
  const float* fc2w = (const float*)d_in[12];
  const float* fc2b = (const float*)d_in[13];
  const float* fc3w = (const float*)d_in[14];
  const float* fc3b = (const float*)d_in[15];
  const float* fc4w = (const float*)d_in[16];
  const float* fc4b = (const float*)d_in[17];
  float* out = (float*)d_out;

  // workspace layout (u16 units then ints, all 16B-aligned): ~56 MB
  u16* zc  = (u16*)d_ws;                        // NNP*416
  u16* PQ  = zc  + (size_t)NNP * KD;            // NNP*800
  u16* W1f = PQ  + (size_t)NNP * 800;           // 332800
  u16* W2f = W1f + W1F_ELEMS;                   // 93184
  u16* W3f = W2f + W2F_ELEMS;                   // 28672
  float* fc4wp = (float*)(W3f + W3F_ELEMS);     // 128 f32
  int* cnt = (int*)(fc4wp + F4_ELEMS);          // 20480
  int* ofs = cnt + CNT_N;                       // 20480
  int* ss  = ofs + CNT_N;                       // 500000
  int* dd  = ss + NE;                           // 500000
  int* eo  = dd + NE;                           // 500000

  hipMemsetAsync(cnt, 0, CNT_N * sizeof(int), stream);
  prep_w<<<(PREP_TOT + 255) / 256, 256, 0, stream>>>(
      fc1w, fc1b, fc2w, fc2b, fc3w, fc3b, fc4w, ei, W1f, W2f, W3f, fc4wp, cnt);
  edge_scan<<<1, 1024, 0, stream>>>(cnt, ofs);
  edge_scatter<<<(NE / 4 + 255) / 256, 256, 0, stream>>>(ei, ofs, ss, dd, eo);
  build_zc<<<NNP / 4, 256, 0, stream>>>(z, cell, esm, w1, b1, w2, b2, w3, b3, zc);
  node_gemm<<<dim3((NNP + 127) / 128, 5), 256, 0, stream>>>(zc, W1f, PQ);
  edge_kernel<<<EGRID, 256, 0, stream>>>(
      PQ, W2f, W3f, fc4wp, fc4b, ss, dd, eo, out);
}